// Round 1
// baseline (2151.650 us; speedup 1.0000x reference)
//
#include <hip/hip_runtime.h>

#define NV 50000
#define EV 800000
#define INF 128
#define HD 64
#define KNEG 5

// ---------------- embed: h = node_feat @ emb_w + emb_b ----------------
__global__ __launch_bounds__(256) void embed_kernel(
    const float* __restrict__ feat, const float* __restrict__ W,
    const float* __restrict__ b, float* __restrict__ h) {
  __shared__ float sW[INF * HD];   // 32 KB
  __shared__ float sF[4][INF];     // 2 KB
  for (int i = threadIdx.x; i < INF * HD; i += 256) sW[i] = W[i];
  const int f = threadIdx.x & 63;
  const int sub = threadIdx.x >> 6;   // wave id within block (wave-uniform)
  const float bias = b[f];
  __syncthreads();
  const int ngroups = (NV + 3) / 4;
  for (int g = blockIdx.x; g < ngroups; g += gridDim.x) {
    const int n0 = g * 4;
    for (int i = threadIdx.x; i < 4 * INF; i += 256) {
      const int nn = n0 + (i >> 7);
      sF[i >> 7][i & 127] = (nn < NV) ? feat[nn * INF + (i & 127)] : 0.f;
    }
    __syncthreads();
    const int n = n0 + sub;
    if (n < NV) {
      float acc = bias;
#pragma unroll 8
      for (int k = 0; k < INF; k++) acc += sF[sub][k] * sW[k * HD + f];
      h[n * HD + f] = acc;
    }
    __syncthreads();
  }
}

// ---------------- degree of each dst node (same for both layers) ------
__global__ __launch_bounds__(256) void deg_kernel(
    const int* __restrict__ dst, int* __restrict__ deg) {
  const int e = blockIdx.x * 256 + threadIdx.x;
  if (e < EV) atomicAdd(&deg[dst[e]], 1);
}

// ---------------- scatter: s1[dst[e]] += h[src[e]] --------------------
// 16 lanes per edge, float4 loads (coalesced), 4 f32 atomics per lane.
__global__ __launch_bounds__(256) void scatter_kernel(
    const float* __restrict__ h, const int* __restrict__ src,
    const int* __restrict__ dst, float* __restrict__ s1) {
  const int tid = blockIdx.x * 256 + threadIdx.x;
  const int e = tid >> 4;
  const int q = tid & 15;
  if (e >= EV) return;
  const int s = src[e];
  const int d = dst[e];
  const float4 v = ((const float4*)(h + (size_t)s * HD))[q];
  float* p = s1 + (size_t)d * HD + q * 4;
  atomicAdd(p + 0, v.x);
  atomicAdd(p + 1, v.y);
  atomicAdd(p + 2, v.z);
  atomicAdd(p + 3, v.w);
}

// ---------------- combine: node-wise transform, in place on h ---------
// agg = s1[n]@w_s + deg[n]*(h[n]@w_d) + deg[n]*cb
// h[n] = relu(bn(sigmoid(agg) + softplus(h[n])))
__global__ __launch_bounds__(256) void combine_kernel(
    float* __restrict__ h, const float* __restrict__ s1,
    const int* __restrict__ deg, const float* __restrict__ wconv,
    const float* __restrict__ cb, const float* __restrict__ gamma,
    const float* __restrict__ beta, const float* __restrict__ mean,
    const float* __restrict__ var) {
  __shared__ float sWs[HD * HD];  // 16 KB
  __shared__ float sWd[HD * HD];  // 16 KB
  __shared__ float sS[4][HD];
  __shared__ float sH[4][HD];
  for (int i = threadIdx.x; i < HD * HD; i += 256) {
    sWs[i] = wconv[i];
    sWd[i] = wconv[HD * HD + i];
  }
  const int f = threadIdx.x & 63;
  const int sub = threadIdx.x >> 6;
  const float cbf = cb[f];
  const float gf = gamma[f];
  const float btf = beta[f];
  const float mf = mean[f];
  const float inv = rsqrtf(var[f] + 1e-3f);
  __syncthreads();
  const int ngroups = (NV + 3) / 4;
  for (int g = blockIdx.x; g < ngroups; g += gridDim.x) {
    const int n0 = g * 4;
    for (int i = threadIdx.x; i < 4 * HD; i += 256) {
      const int nn = n0 + (i >> 6);
      if (nn < NV) {
        sS[i >> 6][i & 63] = s1[(size_t)nn * HD + (i & 63)];
        sH[i >> 6][i & 63] = h[(size_t)nn * HD + (i & 63)];
      }
    }
    __syncthreads();
    const int n = n0 + sub;
    if (n < NV) {
      float a1 = 0.f, a2 = 0.f;
#pragma unroll 8
      for (int k = 0; k < HD; k++) {
        a1 += sS[sub][k] * sWs[k * HD + f];
        a2 += sH[sub][k] * sWd[k * HD + f];
      }
      const float d = (float)deg[n];
      const float agg = a1 + d * a2 + d * cbf;
      const float hv = sH[sub][f];
      const float sig = 1.f / (1.f + __expf(-agg));
      const float sp = fmaxf(hv, 0.f) + log1pf(__expf(-fabsf(hv)));
      float x = sig + sp;
      x = gf * (x - mf) * inv + btf;
      h[(size_t)n * HD + f] = fmaxf(x, 0.f);
    }
    __syncthreads();
  }
}

// ---------------- scores: one wave per edge ---------------------------
// srcw = h[src[e]] * w_rel loaded once; dotted vs dst and 5 neg_dst rows.
__global__ __launch_bounds__(256) void score_kernel(
    const float* __restrict__ h, const int* __restrict__ src,
    const int* __restrict__ dst, const int* __restrict__ neg_dst,
    const float* __restrict__ wrel, float* __restrict__ out) {
  const int tid = blockIdx.x * 256 + threadIdx.x;
  const int e = tid >> 6;       // wave-uniform
  const int lane = tid & 63;
  if (e >= EV) return;
  const float w = wrel[lane];
  const int s = src[e];
  const float sv = h[(size_t)s * HD + lane] * w;

  const int d = dst[e];
  float p = sv * h[(size_t)d * HD + lane];
#pragma unroll
  for (int off = 32; off; off >>= 1) p += __shfl_xor(p, off, 64);
  if (lane == 0) out[e] = p;

#pragma unroll
  for (int r = 0; r < KNEG; r++) {
    const int nd = neg_dst[e * KNEG + r];
    float q = sv * h[(size_t)nd * HD + lane];
#pragma unroll
    for (int off = 32; off; off >>= 1) q += __shfl_xor(q, off, 64);
    if (lane == 0) out[(size_t)EV + (size_t)e * KNEG + r] = q;
  }
}

extern "C" void kernel_launch(void* const* d_in, const int* in_sizes, int n_in,
                              void* d_out, int out_size, void* d_ws, size_t ws_size,
                              hipStream_t stream) {
  const float* node_feat = (const float*)d_in[0];   // N x 128
  const float* emb_w     = (const float*)d_in[1];   // 128 x 64
  const float* emb_b     = (const float*)d_in[2];   // 64
  const float* conv_w    = (const float*)d_in[3];   // L x 128 x 64
  const float* conv_b    = (const float*)d_in[4];   // L x 64
  const float* bn_gamma  = (const float*)d_in[5];   // L x 64
  const float* bn_beta   = (const float*)d_in[6];
  const float* bn_mean   = (const float*)d_in[7];
  const float* bn_var    = (const float*)d_in[8];
  const float* w_rel     = (const float*)d_in[9];   // 64
  const int*   src       = (const int*)d_in[10];    // E
  const int*   dst       = (const int*)d_in[11];    // E
  const int*   neg_dst   = (const int*)d_in[12];    // E*K
  float* out = (float*)d_out;                       // E + E*K

  // workspace layout: h (N*H f32) | s1 (N*H f32) | deg (N i32)
  float* h  = (float*)d_ws;
  float* s1 = h + (size_t)NV * HD;
  int*   deg = (int*)(s1 + (size_t)NV * HD);

  hipMemsetAsync(deg, 0, (size_t)NV * sizeof(int), stream);
  embed_kernel<<<1024, 256, 0, stream>>>(node_feat, emb_w, emb_b, h);
  deg_kernel<<<(EV + 255) / 256, 256, 0, stream>>>(dst, deg);

  for (int i = 0; i < 2; i++) {
    hipMemsetAsync(s1, 0, (size_t)NV * HD * sizeof(float), stream);
    scatter_kernel<<<(EV * 16 + 255) / 256, 256, 0, stream>>>(h, src, dst, s1);
    combine_kernel<<<1024, 256, 0, stream>>>(
        h, s1, deg, conv_w + (size_t)i * 2 * HD * HD, conv_b + i * HD,
        bn_gamma + i * HD, bn_beta + i * HD, bn_mean + i * HD, bn_var + i * HD);
  }

  score_kernel<<<((size_t)EV * 64 + 255) / 256, 256, 0, stream>>>(
      h, src, dst, neg_dst, w_rel, out);
}

// Round 2
// 931.355 us; speedup vs baseline: 2.3102x; 2.3102x over previous
//
#include <hip/hip_runtime.h>

#define NV 50000
#define EV 800000
#define INF 128
#define HD 64
#define KNEG 5

// ---------------- embed: h = node_feat @ emb_w + emb_b ----------------
__global__ __launch_bounds__(256) void embed_kernel(
    const float* __restrict__ feat, const float* __restrict__ W,
    const float* __restrict__ b, float* __restrict__ h) {
  __shared__ float sW[INF * HD];   // 32 KB
  __shared__ float sF[4][INF];     // 2 KB
  for (int i = threadIdx.x; i < INF * HD; i += 256) sW[i] = W[i];
  const int f = threadIdx.x & 63;
  const int sub = threadIdx.x >> 6;   // wave id within block (wave-uniform)
  const float bias = b[f];
  __syncthreads();
  const int ngroups = (NV + 3) / 4;
  for (int g = blockIdx.x; g < ngroups; g += gridDim.x) {
    const int n0 = g * 4;
    for (int i = threadIdx.x; i < 4 * INF; i += 256) {
      const int nn = n0 + (i >> 7);
      sF[i >> 7][i & 127] = (nn < NV) ? feat[nn * INF + (i & 127)] : 0.f;
    }
    __syncthreads();
    const int n = n0 + sub;
    if (n < NV) {
      float acc = bias;
#pragma unroll 8
      for (int k = 0; k < INF; k++) acc += sF[sub][k] * sW[k * HD + f];
      h[n * HD + f] = acc;
    }
    __syncthreads();
  }
}

// ---------------- degree histogram (in-degree over dst) ---------------
__global__ __launch_bounds__(256) void hist_kernel(
    const int* __restrict__ dst, int* __restrict__ deg) {
  const int e = blockIdx.x * 256 + threadIdx.x;
  if (e < EV) atomicAdd(&deg[dst[e]], 1);
}

// ---------------- exclusive scan of deg -> off (single block) ---------
__global__ __launch_bounds__(1024) void scan_kernel(
    const int* __restrict__ deg, int* __restrict__ off) {
  __shared__ int wscan[16];
  const int tid = threadIdx.x;
  const int lane = tid & 63;
  const int w = tid >> 6;
  int carry = 0;
  const int NTILES = (NV + 1023) / 1024;
  for (int t = 0; t < NTILES; t++) {
    const int i = t * 1024 + tid;
    const int v = (i < NV) ? deg[i] : 0;
    int s = v;
#pragma unroll
    for (int ofs = 1; ofs < 64; ofs <<= 1) {
      int x = __shfl_up(s, ofs, 64);
      if (lane >= ofs) s += x;
    }
    if (lane == 63) wscan[w] = s;
    __syncthreads();
    if (w == 0) {
      int t2 = (lane < 16) ? wscan[lane] : 0;
#pragma unroll
      for (int ofs = 1; ofs < 16; ofs <<= 1) {
        int x = __shfl_up(t2, ofs, 64);
        if (lane >= ofs) t2 += x;
      }
      if (lane < 16) wscan[lane] = t2;
    }
    __syncthreads();
    const int base = carry + ((w > 0) ? wscan[w - 1] : 0);
    if (i < NV) off[i] = base + s - v;   // exclusive prefix
    carry += wscan[15];
    __syncthreads();
  }
  if (tid == 0) off[NV] = carry;         // == EV
}

// ---------------- CSR perm: gsrc[pos] = src[e], grouped by dst --------
__global__ __launch_bounds__(256) void perm_kernel(
    const int* __restrict__ src, const int* __restrict__ dst,
    int* __restrict__ cursor, int* __restrict__ gsrc) {
  const int e = blockIdx.x * 256 + threadIdx.x;
  if (e < EV) {
    const int pos = atomicAdd(&cursor[dst[e]], 1);
    gsrc[pos] = src[e];
  }
}

// ---------------- aggregate: one wave per node, no atomics ------------
__global__ __launch_bounds__(256) void aggregate_kernel(
    const float* __restrict__ h, const int* __restrict__ gsrc,
    const int* __restrict__ off, float* __restrict__ s1) {
  const int lane = threadIdx.x & 63;
  const int n = (blockIdx.x * 256 + threadIdx.x) >> 6;  // global wave id
  if (n >= NV) return;
  const int j0 = off[n], j1 = off[n + 1];
  float acc = 0.f;
  int j = j0;
  for (; j + 4 <= j1; j += 4) {
    const int a0 = gsrc[j], a1 = gsrc[j + 1], a2 = gsrc[j + 2], a3 = gsrc[j + 3];
    const float v0 = h[(size_t)a0 * HD + lane];
    const float v1 = h[(size_t)a1 * HD + lane];
    const float v2 = h[(size_t)a2 * HD + lane];
    const float v3 = h[(size_t)a3 * HD + lane];
    acc += (v0 + v1) + (v2 + v3);
  }
  for (; j < j1; j++) acc += h[(size_t)gsrc[j] * HD + lane];
  s1[(size_t)n * HD + lane] = acc;
}

// ---------------- combine: node-wise transform, in place on h ---------
__global__ __launch_bounds__(256) void combine_kernel(
    float* __restrict__ h, const float* __restrict__ s1,
    const int* __restrict__ off, const float* __restrict__ wconv,
    const float* __restrict__ cb, const float* __restrict__ gamma,
    const float* __restrict__ beta, const float* __restrict__ mean,
    const float* __restrict__ var) {
  __shared__ float sWs[HD * HD];  // 16 KB
  __shared__ float sWd[HD * HD];  // 16 KB
  __shared__ float sS[4][HD];
  __shared__ float sH[4][HD];
  for (int i = threadIdx.x; i < HD * HD; i += 256) {
    sWs[i] = wconv[i];
    sWd[i] = wconv[HD * HD + i];
  }
  const int f = threadIdx.x & 63;
  const int sub = threadIdx.x >> 6;
  const float cbf = cb[f];
  const float gf = gamma[f];
  const float btf = beta[f];
  const float mf = mean[f];
  const float inv = rsqrtf(var[f] + 1e-3f);
  __syncthreads();
  const int ngroups = (NV + 3) / 4;
  for (int g = blockIdx.x; g < ngroups; g += gridDim.x) {
    const int n0 = g * 4;
    for (int i = threadIdx.x; i < 4 * HD; i += 256) {
      const int nn = n0 + (i >> 6);
      if (nn < NV) {
        sS[i >> 6][i & 63] = s1[(size_t)nn * HD + (i & 63)];
        sH[i >> 6][i & 63] = h[(size_t)nn * HD + (i & 63)];
      }
    }
    __syncthreads();
    const int n = n0 + sub;
    if (n < NV) {
      float a1 = 0.f, a2 = 0.f;
#pragma unroll 8
      for (int k = 0; k < HD; k++) {
        a1 += sS[sub][k] * sWs[k * HD + f];
        a2 += sH[sub][k] * sWd[k * HD + f];
      }
      const float d = (float)(off[n + 1] - off[n]);
      const float agg = a1 + d * a2 + d * cbf;
      const float hv = sH[sub][f];
      const float sig = 1.f / (1.f + __expf(-agg));
      const float sp = fmaxf(hv, 0.f) + log1pf(__expf(-fabsf(hv)));
      float x = sig + sp;
      x = gf * (x - mf) * inv + btf;
      h[(size_t)n * HD + f] = fmaxf(x, 0.f);
    }
    __syncthreads();
  }
}

// ---------------- scores: one wave per edge ---------------------------
__global__ __launch_bounds__(256) void score_kernel(
    const float* __restrict__ h, const int* __restrict__ src,
    const int* __restrict__ dst, const int* __restrict__ neg_dst,
    const float* __restrict__ wrel, float* __restrict__ out) {
  const int tid = blockIdx.x * 256 + threadIdx.x;
  const int e = tid >> 6;       // wave-uniform
  const int lane = tid & 63;
  if (e >= EV) return;
  const float w = wrel[lane];
  const int s = src[e];
  const float sv = h[(size_t)s * HD + lane] * w;

  const int d = dst[e];
  float p = sv * h[(size_t)d * HD + lane];
#pragma unroll
  for (int off = 32; off; off >>= 1) p += __shfl_xor(p, off, 64);
  if (lane == 0) out[e] = p;

#pragma unroll
  for (int r = 0; r < KNEG; r++) {
    const int nd = neg_dst[e * KNEG + r];
    float q = sv * h[(size_t)nd * HD + lane];
#pragma unroll
    for (int off = 32; off; off >>= 1) q += __shfl_xor(q, off, 64);
    if (lane == 0) out[(size_t)EV + (size_t)e * KNEG + r] = q;
  }
}

extern "C" void kernel_launch(void* const* d_in, const int* in_sizes, int n_in,
                              void* d_out, int out_size, void* d_ws, size_t ws_size,
                              hipStream_t stream) {
  const float* node_feat = (const float*)d_in[0];   // N x 128
  const float* emb_w     = (const float*)d_in[1];   // 128 x 64
  const float* emb_b     = (const float*)d_in[2];   // 64
  const float* conv_w    = (const float*)d_in[3];   // L x 128 x 64
  const float* conv_b    = (const float*)d_in[4];   // L x 64
  const float* bn_gamma  = (const float*)d_in[5];   // L x 64
  const float* bn_beta   = (const float*)d_in[6];
  const float* bn_mean   = (const float*)d_in[7];
  const float* bn_var    = (const float*)d_in[8];
  const float* w_rel     = (const float*)d_in[9];   // 64
  const int*   src       = (const int*)d_in[10];    // E
  const int*   dst       = (const int*)d_in[11];    // E
  const int*   neg_dst   = (const int*)d_in[12];    // E*K
  float* out = (float*)d_out;                       // E + E*K

  // ws layout: h (N*H f32) | s1 (N*H f32) | off (N+1 i32) | gsrc (E i32)
  // deg and cursor alias the s1 region (dead before aggregate writes s1).
  float* h   = (float*)d_ws;
  float* s1  = h + (size_t)NV * HD;
  int*   off = (int*)(s1 + (size_t)NV * HD);
  int*   gsrc = off + (NV + 1);
  int*   deg = (int*)s1;           // alias: s1[0 .. NV)
  int*   cursor = ((int*)s1) + NV; // alias: s1[NV .. 2NV)

  hipMemsetAsync(deg, 0, (size_t)NV * sizeof(int), stream);
  embed_kernel<<<1024, 256, 0, stream>>>(node_feat, emb_w, emb_b, h);
  hist_kernel<<<(EV + 255) / 256, 256, 0, stream>>>(dst, deg);
  scan_kernel<<<1, 1024, 0, stream>>>(deg, off);
  hipMemcpyAsync(cursor, off, (size_t)NV * sizeof(int),
                 hipMemcpyDeviceToDevice, stream);
  perm_kernel<<<(EV + 255) / 256, 256, 0, stream>>>(src, dst, cursor, gsrc);

  for (int i = 0; i < 2; i++) {
    aggregate_kernel<<<(NV * 64 + 255) / 256, 256, 0, stream>>>(h, gsrc, off, s1);
    combine_kernel<<<1024, 256, 0, stream>>>(
        h, s1, off, conv_w + (size_t)i * 2 * HD * HD, conv_b + i * HD,
        bn_gamma + i * HD, bn_beta + i * HD, bn_mean + i * HD, bn_var + i * HD);
  }

  score_kernel<<<((size_t)EV * 64 + 255) / 256, 256, 0, stream>>>(
      h, src, dst, neg_dst, w_rel, out);
}

// Round 3
// 574.905 us; speedup vs baseline: 3.7426x; 1.6200x over previous
//
#include <hip/hip_runtime.h>

#define NV 50000
#define EV 800000
#define INF 128
#define HD 64
#define KNEG 5

// ---------------- embed: h = node_feat @ emb_w + emb_b ----------------
__global__ __launch_bounds__(256) void embed_kernel(
    const float* __restrict__ feat, const float* __restrict__ W,
    const float* __restrict__ b, float* __restrict__ h) {
  __shared__ float sW[INF * HD];   // 32 KB
  __shared__ float sF[4][INF];     // 2 KB
  for (int i = threadIdx.x; i < INF * HD; i += 256) sW[i] = W[i];
  const int f = threadIdx.x & 63;
  const int sub = threadIdx.x >> 6;   // wave id within block (wave-uniform)
  const float bias = b[f];
  __syncthreads();
  const int ngroups = (NV + 3) / 4;
  for (int g = blockIdx.x; g < ngroups; g += gridDim.x) {
    const int n0 = g * 4;
    for (int i = threadIdx.x; i < 4 * INF; i += 256) {
      const int nn = n0 + (i >> 7);
      sF[i >> 7][i & 127] = (nn < NV) ? feat[nn * INF + (i & 127)] : 0.f;
    }
    __syncthreads();
    const int n = n0 + sub;
    if (n < NV) {
      float acc = bias;
#pragma unroll 8
      for (int k = 0; k < INF; k++) acc += sF[sub][k] * sW[k * HD + f];
      h[n * HD + f] = acc;
    }
    __syncthreads();
  }
}

// ---------------- degree histogram (in-degree over dst) ---------------
__global__ __launch_bounds__(256) void hist_kernel(
    const int* __restrict__ dst, int* __restrict__ deg) {
  const int e = blockIdx.x * 256 + threadIdx.x;
  if (e < EV) atomicAdd(&deg[dst[e]], 1);
}

// ---------------- exclusive scan of deg -> off (single block) ---------
__global__ __launch_bounds__(1024) void scan_kernel(
    const int* __restrict__ deg, int* __restrict__ off) {
  __shared__ int wscan[16];
  const int tid = threadIdx.x;
  const int lane = tid & 63;
  const int w = tid >> 6;
  int carry = 0;
  const int NTILES = (NV + 1023) / 1024;
  for (int t = 0; t < NTILES; t++) {
    const int i = t * 1024 + tid;
    const int v = (i < NV) ? deg[i] : 0;
    int s = v;
#pragma unroll
    for (int ofs = 1; ofs < 64; ofs <<= 1) {
      int x = __shfl_up(s, ofs, 64);
      if (lane >= ofs) s += x;
    }
    if (lane == 63) wscan[w] = s;
    __syncthreads();
    if (w == 0) {
      int t2 = (lane < 16) ? wscan[lane] : 0;
#pragma unroll
      for (int ofs = 1; ofs < 16; ofs <<= 1) {
        int x = __shfl_up(t2, ofs, 64);
        if (lane >= ofs) t2 += x;
      }
      if (lane < 16) wscan[lane] = t2;
    }
    __syncthreads();
    const int base = carry + ((w > 0) ? wscan[w - 1] : 0);
    if (i < NV) off[i] = base + s - v;   // exclusive prefix
    carry += wscan[15];
    __syncthreads();
  }
  if (tid == 0) off[NV] = carry;         // == EV
}

// ---------------- CSR perm: gsrc[pos] = src[e], grouped by dst --------
__global__ __launch_bounds__(256) void perm_kernel(
    const int* __restrict__ src, const int* __restrict__ dst,
    int* __restrict__ cursor, int* __restrict__ gsrc) {
  const int e = blockIdx.x * 256 + threadIdx.x;
  if (e < EV) {
    const int pos = atomicAdd(&cursor[dst[e]], 1);
    gsrc[pos] = src[e];
  }
}

// ---------------- aggregate: one wave per node, 4 edges/iter ----------
// 16 lanes x float4 cover one 64-float row; sub = which of 4 edges.
__global__ __launch_bounds__(256) void aggregate_kernel(
    const float* __restrict__ h, const int* __restrict__ gsrc,
    const int* __restrict__ off, float* __restrict__ s1) {
  const int n = (blockIdx.x * 256 + threadIdx.x) >> 6;  // global wave id
  const int lane = threadIdx.x & 63;
  const int sub = lane >> 4;   // edge slot 0..3
  const int q = lane & 15;     // float4 slot within row
  if (n >= NV) return;
  const int j0 = off[n], j1 = off[n + 1];
  const float4* hp = (const float4*)h;
  float4 acc = make_float4(0.f, 0.f, 0.f, 0.f);
  int j = j0;
  for (; j + 4 <= j1; j += 4) {
    const int a = gsrc[j + sub];
    const float4 v = hp[(size_t)a * 16 + q];
    acc.x += v.x; acc.y += v.y; acc.z += v.z; acc.w += v.w;
  }
  if (j + sub < j1) {
    const int a = gsrc[j + sub];
    const float4 v = hp[(size_t)a * 16 + q];
    acc.x += v.x; acc.y += v.y; acc.z += v.z; acc.w += v.w;
  }
#pragma unroll
  for (int m = 16; m <= 32; m <<= 1) {
    acc.x += __shfl_xor(acc.x, m, 64);
    acc.y += __shfl_xor(acc.y, m, 64);
    acc.z += __shfl_xor(acc.z, m, 64);
    acc.w += __shfl_xor(acc.w, m, 64);
  }
  if (sub == 0) ((float4*)(s1 + (size_t)n * HD))[q] = acc;
}

// ---------------- combine: node-wise transform, in place on h ---------
__global__ __launch_bounds__(256) void combine_kernel(
    float* __restrict__ h, const float* __restrict__ s1,
    const int* __restrict__ off, const float* __restrict__ wconv,
    const float* __restrict__ cb, const float* __restrict__ gamma,
    const float* __restrict__ beta, const float* __restrict__ mean,
    const float* __restrict__ var) {
  __shared__ float sWs[HD * HD];  // 16 KB
  __shared__ float sWd[HD * HD];  // 16 KB
  __shared__ float sS[4][HD];
  __shared__ float sH[4][HD];
  for (int i = threadIdx.x; i < HD * HD; i += 256) {
    sWs[i] = wconv[i];
    sWd[i] = wconv[HD * HD + i];
  }
  const int f = threadIdx.x & 63;
  const int sub = threadIdx.x >> 6;
  const float cbf = cb[f];
  const float gf = gamma[f];
  const float btf = beta[f];
  const float mf = mean[f];
  const float inv = rsqrtf(var[f] + 1e-3f);
  __syncthreads();
  const int ngroups = (NV + 3) / 4;
  for (int g = blockIdx.x; g < ngroups; g += gridDim.x) {
    const int n0 = g * 4;
    for (int i = threadIdx.x; i < 4 * HD; i += 256) {
      const int nn = n0 + (i >> 6);
      if (nn < NV) {
        sS[i >> 6][i & 63] = s1[(size_t)nn * HD + (i & 63)];
        sH[i >> 6][i & 63] = h[(size_t)nn * HD + (i & 63)];
      }
    }
    __syncthreads();
    const int n = n0 + sub;
    if (n < NV) {
      float a1 = 0.f, a2 = 0.f;
#pragma unroll 8
      for (int k = 0; k < HD; k++) {
        a1 += sS[sub][k] * sWs[k * HD + f];
        a2 += sH[sub][k] * sWd[k * HD + f];
      }
      const float d = (float)(off[n + 1] - off[n]);
      const float agg = a1 + d * a2 + d * cbf;
      const float hv = sH[sub][f];
      const float sig = 1.f / (1.f + __expf(-agg));
      const float sp = fmaxf(hv, 0.f) + log1pf(__expf(-fabsf(hv)));
      float x = sig + sp;
      x = gf * (x - mf) * inv + btf;
      h[(size_t)n * HD + f] = fmaxf(x, 0.f);
    }
    __syncthreads();
  }
}

// ---------------- scores: 16 lanes per edge, float4 rows --------------
__global__ __launch_bounds__(256) void score_kernel(
    const float* __restrict__ h, const int* __restrict__ src,
    const int* __restrict__ dst, const int* __restrict__ neg_dst,
    const float* __restrict__ wrel, float* __restrict__ out) {
  const int tid = blockIdx.x * 256 + threadIdx.x;
  const int e = tid >> 4;       // 4 edges per wave
  const int q = tid & 15;       // float4 slot within row
  if (e >= EV) return;
  const float4 w = ((const float4*)wrel)[q];
  const int s = src[e];
  const int d = dst[e];
  int nd[KNEG];
#pragma unroll
  for (int r = 0; r < KNEG; r++) nd[r] = neg_dst[e * KNEG + r];

  const float4* hp = (const float4*)h;
  const float4 sv = hp[(size_t)s * 16 + q];
  const float4 dv = hp[(size_t)d * 16 + q];
  float4 nv[KNEG];
#pragma unroll
  for (int r = 0; r < KNEG; r++) nv[r] = hp[(size_t)nd[r] * 16 + q];

  const float swx = sv.x * w.x, swy = sv.y * w.y, swz = sv.z * w.z, sww = sv.w * w.w;

  float p = swx * dv.x + swy * dv.y + swz * dv.z + sww * dv.w;
#pragma unroll
  for (int m = 8; m; m >>= 1) p += __shfl_xor(p, m, 64);
  if (q == 0) out[e] = p;

#pragma unroll
  for (int r = 0; r < KNEG; r++) {
    float pn = swx * nv[r].x + swy * nv[r].y + swz * nv[r].z + sww * nv[r].w;
#pragma unroll
    for (int m = 8; m; m >>= 1) pn += __shfl_xor(pn, m, 64);
    if (q == 0) out[(size_t)EV + (size_t)e * KNEG + r] = pn;
  }
}

extern "C" void kernel_launch(void* const* d_in, const int* in_sizes, int n_in,
                              void* d_out, int out_size, void* d_ws, size_t ws_size,
                              hipStream_t stream) {
  const float* node_feat = (const float*)d_in[0];   // N x 128
  const float* emb_w     = (const float*)d_in[1];   // 128 x 64
  const float* emb_b     = (const float*)d_in[2];   // 64
  const float* conv_w    = (const float*)d_in[3];   // L x 128 x 64
  const float* conv_b    = (const float*)d_in[4];   // L x 64
  const float* bn_gamma  = (const float*)d_in[5];   // L x 64
  const float* bn_beta   = (const float*)d_in[6];
  const float* bn_mean   = (const float*)d_in[7];
  const float* bn_var    = (const float*)d_in[8];
  const float* w_rel     = (const float*)d_in[9];   // 64
  const int*   src       = (const int*)d_in[10];    // E
  const int*   dst       = (const int*)d_in[11];    // E
  const int*   neg_dst   = (const int*)d_in[12];    // E*K
  float* out = (float*)d_out;                       // E + E*K

  // ws layout: h (N*H f32) | s1 (N*H f32) | off (N+1 i32) | gsrc (E i32)
  // deg and cursor alias the s1 region (dead before aggregate writes s1).
  float* h   = (float*)d_ws;
  float* s1  = h + (size_t)NV * HD;
  int*   off = (int*)(s1 + (size_t)NV * HD);
  int*   gsrc = off + (NV + 1);
  int*   deg = (int*)s1;           // alias: s1[0 .. NV)
  int*   cursor = ((int*)s1) + NV; // alias: s1[NV .. 2NV)

  hipMemsetAsync(deg, 0, (size_t)NV * sizeof(int), stream);
  embed_kernel<<<1024, 256, 0, stream>>>(node_feat, emb_w, emb_b, h);
  hist_kernel<<<(EV + 255) / 256, 256, 0, stream>>>(dst, deg);
  scan_kernel<<<1, 1024, 0, stream>>>(deg, off);
  hipMemcpyAsync(cursor, off, (size_t)NV * sizeof(int),
                 hipMemcpyDeviceToDevice, stream);
  perm_kernel<<<(EV + 255) / 256, 256, 0, stream>>>(src, dst, cursor, gsrc);

  for (int i = 0; i < 2; i++) {
    aggregate_kernel<<<(NV + 3) / 4, 256, 0, stream>>>(h, gsrc, off, s1);
    combine_kernel<<<1024, 256, 0, stream>>>(
        h, s1, off, conv_w + (size_t)i * 2 * HD * HD, conv_b + i * HD,
        bn_gamma + i * HD, bn_beta + i * HD, bn_mean + i * HD, bn_var + i * HD);
  }

  score_kernel<<<(EV + 15) / 16, 256, 0, stream>>>(
      h, src, dst, neg_dst, w_rel, out);
}

// Round 5
// 574.678 us; speedup vs baseline: 3.7441x; 1.0004x over previous
//
#include <hip/hip_runtime.h>

#define NV 50000
#define EV 800000
#define INF 128
#define HD 64
#define KNEG 5

// ---------------- embed: h = node_feat @ emb_w + emb_b ----------------
__global__ __launch_bounds__(256) void embed_kernel(
    const float* __restrict__ feat, const float* __restrict__ W,
    const float* __restrict__ b, float* __restrict__ h) {
  __shared__ float sW[INF * HD];   // 32 KB
  __shared__ float sF[4][INF];     // 2 KB
  for (int i = threadIdx.x; i < INF * HD; i += 256) sW[i] = W[i];
  const int f = threadIdx.x & 63;
  const int sub = threadIdx.x >> 6;   // wave id within block (wave-uniform)
  const float bias = b[f];
  __syncthreads();
  const int ngroups = (NV + 3) / 4;
  for (int g = blockIdx.x; g < ngroups; g += gridDim.x) {
    const int n0 = g * 4;
    for (int i = threadIdx.x; i < 4 * INF; i += 256) {
      const int nn = n0 + (i >> 7);
      sF[i >> 7][i & 127] = (nn < NV) ? feat[nn * INF + (i & 127)] : 0.f;
    }
    __syncthreads();
    const int n = n0 + sub;
    if (n < NV) {
      float acc = bias;
#pragma unroll 8
      for (int k = 0; k < INF; k++) acc += sF[sub][k] * sW[k * HD + f];
      h[n * HD + f] = acc;
    }
    __syncthreads();
  }
}

// ---------------- degree histogram (in-degree over dst) ---------------
__global__ __launch_bounds__(256) void hist_kernel(
    const int* __restrict__ dst, int* __restrict__ deg) {
  const int e = blockIdx.x * 256 + threadIdx.x;
  if (e < EV) atomicAdd(&deg[dst[e]], 1);
}

// ---------------- exclusive scan of deg -> off (single block) ---------
__global__ __launch_bounds__(1024) void scan_kernel(
    const int* __restrict__ deg, int* __restrict__ off) {
  __shared__ int wscan[16];
  const int tid = threadIdx.x;
  const int lane = tid & 63;
  const int w = tid >> 6;
  int carry = 0;
  const int NTILES = (NV + 1023) / 1024;
  for (int t = 0; t < NTILES; t++) {
    const int i = t * 1024 + tid;
    const int v = (i < NV) ? deg[i] : 0;
    int s = v;
#pragma unroll
    for (int ofs = 1; ofs < 64; ofs <<= 1) {
      int x = __shfl_up(s, ofs, 64);
      if (lane >= ofs) s += x;
    }
    if (lane == 63) wscan[w] = s;
    __syncthreads();
    if (w == 0) {
      int t2 = (lane < 16) ? wscan[lane] : 0;
#pragma unroll
      for (int ofs = 1; ofs < 16; ofs <<= 1) {
        int x = __shfl_up(t2, ofs, 64);
        if (lane >= ofs) t2 += x;
      }
      if (lane < 16) wscan[lane] = t2;
    }
    __syncthreads();
    const int base = carry + ((w > 0) ? wscan[w - 1] : 0);
    if (i < NV) off[i] = base + s - v;   // exclusive prefix
    carry += wscan[15];
    __syncthreads();
  }
  if (tid == 0) off[NV] = carry;         // == EV
}

// ---------------- CSR perm: gsrc[pos] = src[e], grouped by dst --------
__global__ __launch_bounds__(256) void perm_kernel(
    const int* __restrict__ src, const int* __restrict__ dst,
    int* __restrict__ cursor, int* __restrict__ gsrc) {
  const int e = blockIdx.x * 256 + threadIdx.x;
  if (e < EV) {
    const int pos = atomicAdd(&cursor[dst[e]], 1);
    gsrc[pos] = src[e];
  }
}

// ---------------- aggregate: one wave per node, 4 edges/iter ----------
// 16 lanes x float4 cover one 64-float row; sub = which of 4 edges.
__global__ __launch_bounds__(256) void aggregate_kernel(
    const float* __restrict__ h, const int* __restrict__ gsrc,
    const int* __restrict__ off, float* __restrict__ s1) {
  const int n = (blockIdx.x * 256 + threadIdx.x) >> 6;  // global wave id
  const int lane = threadIdx.x & 63;
  const int sub = lane >> 4;   // edge slot 0..3
  const int q = lane & 15;     // float4 slot within row
  if (n >= NV) return;
  const int j0 = off[n], j1 = off[n + 1];
  const float4* hp = (const float4*)h;
  float4 acc = make_float4(0.f, 0.f, 0.f, 0.f);
  int j = j0;
  for (; j + 4 <= j1; j += 4) {
    const int a = gsrc[j + sub];
    const float4 v = hp[(size_t)a * 16 + q];
    acc.x += v.x; acc.y += v.y; acc.z += v.z; acc.w += v.w;
  }
  if (j + sub < j1) {
    const int a = gsrc[j + sub];
    const float4 v = hp[(size_t)a * 16 + q];
    acc.x += v.x; acc.y += v.y; acc.z += v.z; acc.w += v.w;
  }
#pragma unroll
  for (int m = 16; m <= 32; m <<= 1) {
    acc.x += __shfl_xor(acc.x, m, 64);
    acc.y += __shfl_xor(acc.y, m, 64);
    acc.z += __shfl_xor(acc.z, m, 64);
    acc.w += __shfl_xor(acc.w, m, 64);
  }
  if (sub == 0) ((float4*)(s1 + (size_t)n * HD))[q] = acc;
}

// ---------------- combine: node-wise transform, in place on h ---------
__global__ __launch_bounds__(256) void combine_kernel(
    float* __restrict__ h, const float* __restrict__ s1,
    const int* __restrict__ off, const float* __restrict__ wconv,
    const float* __restrict__ cb, const float* __restrict__ gamma,
    const float* __restrict__ beta, const float* __restrict__ mean,
    const float* __restrict__ var) {
  __shared__ float sWs[HD * HD];  // 16 KB
  __shared__ float sWd[HD * HD];  // 16 KB
  __shared__ float sS[4][HD];
  __shared__ float sH[4][HD];
  for (int i = threadIdx.x; i < HD * HD; i += 256) {
    sWs[i] = wconv[i];
    sWd[i] = wconv[HD * HD + i];
  }
  const int f = threadIdx.x & 63;
  const int sub = threadIdx.x >> 6;
  const float cbf = cb[f];
  const float gf = gamma[f];
  const float btf = beta[f];
  const float mf = mean[f];
  const float inv = rsqrtf(var[f] + 1e-3f);
  __syncthreads();
  const int ngroups = (NV + 3) / 4;
  for (int g = blockIdx.x; g < ngroups; g += gridDim.x) {
    const int n0 = g * 4;
    for (int i = threadIdx.x; i < 4 * HD; i += 256) {
      const int nn = n0 + (i >> 6);
      if (nn < NV) {
        sS[i >> 6][i & 63] = s1[(size_t)nn * HD + (i & 63)];
        sH[i >> 6][i & 63] = h[(size_t)nn * HD + (i & 63)];
      }
    }
    __syncthreads();
    const int n = n0 + sub;
    if (n < NV) {
      float a1 = 0.f, a2 = 0.f;
#pragma unroll 8
      for (int k = 0; k < HD; k++) {
        a1 += sS[sub][k] * sWs[k * HD + f];
        a2 += sH[sub][k] * sWd[k * HD + f];
      }
      const float d = (float)(off[n + 1] - off[n]);
      const float agg = a1 + d * a2 + d * cbf;
      const float hv = sH[sub][f];
      const float sig = 1.f / (1.f + __expf(-agg));
      const float sp = fmaxf(hv, 0.f) + log1pf(__expf(-fabsf(hv)));
      float x = sig + sp;
      x = gf * (x - mf) * inv + btf;
      h[(size_t)n * HD + f] = fmaxf(x, 0.f);
    }
    __syncthreads();
  }
}

// ---------------- scores: 8 lanes per edge, 2 float4 per thread -------
__global__ __launch_bounds__(256) void score_kernel(
    const float* __restrict__ h, const int* __restrict__ src,
    const int* __restrict__ dst, const int* __restrict__ neg_dst,
    const float* __restrict__ wrel, float* __restrict__ out) {
  const int tid = blockIdx.x * 256 + threadIdx.x;
  const int e = tid >> 3;       // 8 edges per wave
  const int q = tid & 7;        // covers float4 slots 2q, 2q+1
  if (e >= EV) return;
  const float4 w0 = ((const float4*)wrel)[2 * q];
  const float4 w1 = ((const float4*)wrel)[2 * q + 1];
  const int s = src[e];
  const int d = dst[e];
  int nd[KNEG];
#pragma unroll
  for (int r = 0; r < KNEG; r++) nd[r] = neg_dst[e * KNEG + r];

  const float4* hp = (const float4*)h;
  const float4 sv0 = hp[(size_t)s * 16 + 2 * q];
  const float4 sv1 = hp[(size_t)s * 16 + 2 * q + 1];
  const float4 dv0 = hp[(size_t)d * 16 + 2 * q];
  const float4 dv1 = hp[(size_t)d * 16 + 2 * q + 1];
  float4 nv0[KNEG], nv1[KNEG];
#pragma unroll
  for (int r = 0; r < KNEG; r++) {
    nv0[r] = hp[(size_t)nd[r] * 16 + 2 * q];
    nv1[r] = hp[(size_t)nd[r] * 16 + 2 * q + 1];
  }
  const float s0x = sv0.x * w0.x, s0y = sv0.y * w0.y,
              s0z = sv0.z * w0.z, s0w = sv0.w * w0.w;
  const float s1x = sv1.x * w1.x, s1y = sv1.y * w1.y,
              s1z = sv1.z * w1.z, s1w = sv1.w * w1.w;

  float p = s0x * dv0.x + s0y * dv0.y + s0z * dv0.z + s0w * dv0.w
          + s1x * dv1.x + s1y * dv1.y + s1z * dv1.z + s1w * dv1.w;
#pragma unroll
  for (int m = 4; m; m >>= 1) p += __shfl_xor(p, m, 64);
  if (q == 0) out[e] = p;

#pragma unroll
  for (int r = 0; r < KNEG; r++) {
    float pn = s0x * nv0[r].x + s0y * nv0[r].y + s0z * nv0[r].z + s0w * nv0[r].w
             + s1x * nv1[r].x + s1y * nv1[r].y + s1z * nv1[r].z + s1w * nv1[r].w;
#pragma unroll
    for (int m = 4; m; m >>= 1) pn += __shfl_xor(pn, m, 64);
    if (q == 0) out[(size_t)EV + (size_t)e * KNEG + r] = pn;
  }
}

extern "C" void kernel_launch(void* const* d_in, const int* in_sizes, int n_in,
                              void* d_out, int out_size, void* d_ws, size_t ws_size,
                              hipStream_t stream) {
  const float* node_feat = (const float*)d_in[0];   // N x 128
  const float* emb_w     = (const float*)d_in[1];   // 128 x 64
  const float* emb_b     = (const float*)d_in[2];   // 64
  const float* conv_w    = (const float*)d_in[3];   // L x 128 x 64
  const float* conv_b    = (const float*)d_in[4];   // L x 64
  const float* bn_gamma  = (const float*)d_in[5];   // L x 64
  const float* bn_beta   = (const float*)d_in[6];
  const float* bn_mean   = (const float*)d_in[7];
  const float* bn_var    = (const float*)d_in[8];
  const float* w_rel     = (const float*)d_in[9];   // 64
  const int*   src       = (const int*)d_in[10];    // E
  const int*   dst       = (const int*)d_in[11];    // E
  const int*   neg_dst   = (const int*)d_in[12];    // E*K
  float* out = (float*)d_out;                       // E + E*K

  // ws layout: h (N*H f32) | s1 (N*H f32) | off (N+1 i32) | gsrc (E i32)
  // deg and cursor alias the s1 region (dead before aggregate writes s1).
  float* h   = (float*)d_ws;
  float* s1  = h + (size_t)NV * HD;
  int*   off = (int*)(s1 + (size_t)NV * HD);
  int*   gsrc = off + (NV + 1);
  int*   deg = (int*)s1;           // alias: s1[0 .. NV)
  int*   cursor = ((int*)s1) + NV; // alias: s1[NV .. 2NV)

  hipMemsetAsync(deg, 0, (size_t)NV * sizeof(int), stream);
  embed_kernel<<<1024, 256, 0, stream>>>(node_feat, emb_w, emb_b, h);
  hist_kernel<<<(EV + 255) / 256, 256, 0, stream>>>(dst, deg);
  scan_kernel<<<1, 1024, 0, stream>>>(deg, off);
  hipMemcpyAsync(cursor, off, (size_t)NV * sizeof(int),
                 hipMemcpyDeviceToDevice, stream);
  perm_kernel<<<(EV + 255) / 256, 256, 0, stream>>>(src, dst, cursor, gsrc);

  for (int i = 0; i < 2; i++) {
    aggregate_kernel<<<(NV + 3) / 4, 256, 0, stream>>>(h, gsrc, off, s1);
    combine_kernel<<<1024, 256, 0, stream>>>(
        h, s1, off, conv_w + (size_t)i * 2 * HD * HD, conv_b + i * HD,
        bn_gamma + i * HD, bn_beta + i * HD, bn_mean + i * HD, bn_var + i * HD);
  }

  score_kernel<<<((size_t)EV * 8 + 255) / 256, 256, 0, stream>>>(
      h, src, dst, neg_dst, w_rel, out);
}

// Round 8
// 569.406 us; speedup vs baseline: 3.7788x; 1.0093x over previous
//
#include <hip/hip_runtime.h>

#define NV 50000
#define EV 800000
#define INF 128
#define HD 64
#define KNEG 5

// ---------------- embed: h = node_feat @ emb_w + emb_b ----------------
__global__ __launch_bounds__(256) void embed_kernel(
    const float* __restrict__ feat, const float* __restrict__ W,
    const float* __restrict__ b, float* __restrict__ h) {
  __shared__ float sW[INF * HD];   // 32 KB
  __shared__ float sF[4][INF];     // 2 KB
  for (int i = threadIdx.x; i < INF * HD; i += 256) sW[i] = W[i];
  const int f = threadIdx.x & 63;
  const int sub = threadIdx.x >> 6;   // wave id within block (wave-uniform)
  const float bias = b[f];
  __syncthreads();
  const int ngroups = (NV + 3) / 4;
  for (int g = blockIdx.x; g < ngroups; g += gridDim.x) {
    const int n0 = g * 4;
    for (int i = threadIdx.x; i < 4 * INF; i += 256) {
      const int nn = n0 + (i >> 7);
      sF[i >> 7][i & 127] = (nn < NV) ? feat[nn * INF + (i & 127)] : 0.f;
    }
    __syncthreads();
    const int n = n0 + sub;
    if (n < NV) {
      float acc = bias;
#pragma unroll 8
      for (int k = 0; k < INF; k++) acc += sF[sub][k] * sW[k * HD + f];
      h[n * HD + f] = acc;
    }
    __syncthreads();
  }
}

// ---------------- degree histogram (in-degree over dst) ---------------
__global__ __launch_bounds__(256) void hist_kernel(
    const int* __restrict__ dst, int* __restrict__ deg) {
  const int e = blockIdx.x * 256 + threadIdx.x;
  if (e < EV) atomicAdd(&deg[dst[e]], 1);
}

// ---------------- exclusive scan of deg -> off (single block) ---------
__global__ __launch_bounds__(1024) void scan_kernel(
    const int* __restrict__ deg, int* __restrict__ off) {
  __shared__ int wscan[16];
  const int tid = threadIdx.x;
  const int lane = tid & 63;
  const int w = tid >> 6;
  int carry = 0;
  const int NTILES = (NV + 1023) / 1024;
  for (int t = 0; t < NTILES; t++) {
    const int i = t * 1024 + tid;
    const int v = (i < NV) ? deg[i] : 0;
    int s = v;
#pragma unroll
    for (int ofs = 1; ofs < 64; ofs <<= 1) {
      int x = __shfl_up(s, ofs, 64);
      if (lane >= ofs) s += x;
    }
    if (lane == 63) wscan[w] = s;
    __syncthreads();
    if (w == 0) {
      int t2 = (lane < 16) ? wscan[lane] : 0;
#pragma unroll
      for (int ofs = 1; ofs < 16; ofs <<= 1) {
        int x = __shfl_up(t2, ofs, 64);
        if (lane >= ofs) t2 += x;
      }
      if (lane < 16) wscan[lane] = t2;
    }
    __syncthreads();
    const int base = carry + ((w > 0) ? wscan[w - 1] : 0);
    if (i < NV) off[i] = base + s - v;   // exclusive prefix
    carry += wscan[15];
    __syncthreads();
  }
  if (tid == 0) off[NV] = carry;         // == EV
}

// ---------------- CSR perm: gsrc[pos] = src[e], grouped by dst --------
__global__ __launch_bounds__(256) void perm_kernel(
    const int* __restrict__ src, const int* __restrict__ dst,
    int* __restrict__ cursor, int* __restrict__ gsrc) {
  const int e = blockIdx.x * 256 + threadIdx.x;
  if (e < EV) {
    const int pos = atomicAdd(&cursor[dst[e]], 1);
    gsrc[pos] = src[e];
  }
}

// ---------------- aggregate: one wave per node, idx run in registers --
// One coalesced gsrc load covers <=64 edges of the node; indices are
// distributed by shfl. CRITICAL: every __shfl executes under FULL exec
// (wave-uniform control flow) — ds_bpermute reads from EXEC-disabled
// source lanes return 0, which corrupted the divergent-tail variant.
__global__ __launch_bounds__(256) void aggregate_kernel(
    const float* __restrict__ h, const int* __restrict__ gsrc,
    const int* __restrict__ off, float* __restrict__ s1) {
  const int n = (blockIdx.x * 256 + threadIdx.x) >> 6;  // global wave id
  const int lane = threadIdx.x & 63;
  const int sub = lane >> 4;   // edge slot 0..3
  const int q = lane & 15;     // float4 slot within row
  if (n >= NV) return;
  const int j0 = off[n], j1 = off[n + 1];
  const int deg = j1 - j0;
  const float4* hp = (const float4*)h;
  float4 acc0 = make_float4(0.f, 0.f, 0.f, 0.f);
  float4 acc1 = make_float4(0.f, 0.f, 0.f, 0.f);
  for (int base = 0; base < deg; base += 64) {
    const int cnt = min(64, deg - base);          // wave-uniform
    const int my = (lane < cnt) ? gsrc[j0 + base + lane] : 0;
    int k = 0;
    for (; k + 8 <= cnt; k += 8) {                // uniform: full exec
      const int a0 = __shfl(my, k + sub, 64);
      const int a1 = __shfl(my, k + 4 + sub, 64);
      const float4 v0 = hp[(size_t)a0 * 16 + q];
      const float4 v1 = hp[(size_t)a1 * 16 + q];
      acc0.x += v0.x; acc0.y += v0.y; acc0.z += v0.z; acc0.w += v0.w;
      acc1.x += v1.x; acc1.y += v1.y; acc1.z += v1.z; acc1.w += v1.w;
    }
    for (; k + 4 <= cnt; k += 4) {                // uniform: full exec
      const int a0 = __shfl(my, k + sub, 64);
      const float4 v0 = hp[(size_t)a0 * 16 + q];
      acc0.x += v0.x; acc0.y += v0.y; acc0.z += v0.z; acc0.w += v0.w;
    }
    {
      // Tail (<4 edges): shfl hoisted OUT of the divergent guard; the
      // lane index is clamped so every source lane is active.
      const int idx = k + sub;
      const int a0 = __shfl(my, (idx < cnt) ? idx : 0, 64);  // full exec
      if (idx < cnt) {
        const float4 v0 = hp[(size_t)a0 * 16 + q];
        acc1.x += v0.x; acc1.y += v0.y; acc1.z += v0.z; acc1.w += v0.w;
      }
    }
  }
  acc0.x += acc1.x; acc0.y += acc1.y; acc0.z += acc1.z; acc0.w += acc1.w;
#pragma unroll
  for (int m = 16; m <= 32; m <<= 1) {
    acc0.x += __shfl_xor(acc0.x, m, 64);
    acc0.y += __shfl_xor(acc0.y, m, 64);
    acc0.z += __shfl_xor(acc0.z, m, 64);
    acc0.w += __shfl_xor(acc0.w, m, 64);
  }
  if (sub == 0) ((float4*)(s1 + (size_t)n * HD))[q] = acc0;
}

// ---------------- combine: node-wise transform, in place on h ---------
__global__ __launch_bounds__(256) void combine_kernel(
    float* __restrict__ h, const float* __restrict__ s1,
    const int* __restrict__ off, const float* __restrict__ wconv,
    const float* __restrict__ cb, const float* __restrict__ gamma,
    const float* __restrict__ beta, const float* __restrict__ mean,
    const float* __restrict__ var) {
  __shared__ float sWs[HD * HD];  // 16 KB
  __shared__ float sWd[HD * HD];  // 16 KB
  __shared__ float sS[4][HD];
  __shared__ float sH[4][HD];
  for (int i = threadIdx.x; i < HD * HD; i += 256) {
    sWs[i] = wconv[i];
    sWd[i] = wconv[HD * HD + i];
  }
  const int f = threadIdx.x & 63;
  const int sub = threadIdx.x >> 6;
  const float cbf = cb[f];
  const float gf = gamma[f];
  const float btf = beta[f];
  const float mf = mean[f];
  const float inv = rsqrtf(var[f] + 1e-3f);
  __syncthreads();
  const int ngroups = (NV + 3) / 4;
  for (int g = blockIdx.x; g < ngroups; g += gridDim.x) {
    const int n0 = g * 4;
    for (int i = threadIdx.x; i < 4 * HD; i += 256) {
      const int nn = n0 + (i >> 6);
      if (nn < NV) {
        sS[i >> 6][i & 63] = s1[(size_t)nn * HD + (i & 63)];
        sH[i >> 6][i & 63] = h[(size_t)nn * HD + (i & 63)];
      }
    }
    __syncthreads();
    const int n = n0 + sub;
    if (n < NV) {
      float a1 = 0.f, a2 = 0.f;
#pragma unroll 8
      for (int k = 0; k < HD; k++) {
        a1 += sS[sub][k] * sWs[k * HD + f];
        a2 += sH[sub][k] * sWd[k * HD + f];
      }
      const float d = (float)(off[n + 1] - off[n]);
      const float agg = a1 + d * a2 + d * cbf;
      const float hv = sH[sub][f];
      const float sig = 1.f / (1.f + __expf(-agg));
      const float sp = fmaxf(hv, 0.f) + log1pf(__expf(-fabsf(hv)));
      float x = sig + sp;
      x = gf * (x - mf) * inv + btf;
      h[(size_t)n * HD + f] = fmaxf(x, 0.f);
    }
    __syncthreads();
  }
}

// ---------------- scores: 8 lanes per edge, 2 float4 per thread -------
__global__ __launch_bounds__(256) void score_kernel(
    const float* __restrict__ h, const int* __restrict__ src,
    const int* __restrict__ dst, const int* __restrict__ neg_dst,
    const float* __restrict__ wrel, float* __restrict__ out) {
  const int tid = blockIdx.x * 256 + threadIdx.x;
  const int e = tid >> 3;       // 8 edges per wave
  const int q = tid & 7;        // covers float4 slots 2q, 2q+1
  if (e >= EV) return;
  const float4 w0 = ((const float4*)wrel)[2 * q];
  const float4 w1 = ((const float4*)wrel)[2 * q + 1];
  const int s = src[e];
  const int d = dst[e];
  int nd[KNEG];
#pragma unroll
  for (int r = 0; r < KNEG; r++) nd[r] = neg_dst[e * KNEG + r];

  const float4* hp = (const float4*)h;
  const float4 sv0 = hp[(size_t)s * 16 + 2 * q];
  const float4 sv1 = hp[(size_t)s * 16 + 2 * q + 1];
  const float4 dv0 = hp[(size_t)d * 16 + 2 * q];
  const float4 dv1 = hp[(size_t)d * 16 + 2 * q + 1];
  float4 nv0[KNEG], nv1[KNEG];
#pragma unroll
  for (int r = 0; r < KNEG; r++) {
    nv0[r] = hp[(size_t)nd[r] * 16 + 2 * q];
    nv1[r] = hp[(size_t)nd[r] * 16 + 2 * q + 1];
  }
  const float s0x = sv0.x * w0.x, s0y = sv0.y * w0.y,
              s0z = sv0.z * w0.z, s0w = sv0.w * w0.w;
  const float s1x = sv1.x * w1.x, s1y = sv1.y * w1.y,
              s1z = sv1.z * w1.z, s1w = sv1.w * w1.w;

  float p = s0x * dv0.x + s0y * dv0.y + s0z * dv0.z + s0w * dv0.w
          + s1x * dv1.x + s1y * dv1.y + s1z * dv1.z + s1w * dv1.w;
#pragma unroll
  for (int m = 4; m; m >>= 1) p += __shfl_xor(p, m, 64);
  if (q == 0) out[e] = p;

#pragma unroll
  for (int r = 0; r < KNEG; r++) {
    float pn = s0x * nv0[r].x + s0y * nv0[r].y + s0z * nv0[r].z + s0w * nv0[r].w
             + s1x * nv1[r].x + s1y * nv1[r].y + s1z * nv1[r].z + s1w * nv1[r].w;
#pragma unroll
    for (int m = 4; m; m >>= 1) pn += __shfl_xor(pn, m, 64);
    if (q == 0) out[(size_t)EV + (size_t)e * KNEG + r] = pn;
  }
}

extern "C" void kernel_launch(void* const* d_in, const int* in_sizes, int n_in,
                              void* d_out, int out_size, void* d_ws, size_t ws_size,
                              hipStream_t stream) {
  const float* node_feat = (const float*)d_in[0];   // N x 128
  const float* emb_w     = (const float*)d_in[1];   // 128 x 64
  const float* emb_b     = (const float*)d_in[2];   // 64
  const float* conv_w    = (const float*)d_in[3];   // L x 128 x 64
  const float* conv_b    = (const float*)d_in[4];   // L x 64
  const float* bn_gamma  = (const float*)d_in[5];   // L x 64
  const float* bn_beta   = (const float*)d_in[6];
  const float* bn_mean   = (const float*)d_in[7];
  const float* bn_var    = (const float*)d_in[8];
  const float* w_rel     = (const float*)d_in[9];   // 64
  const int*   src       = (const int*)d_in[10];    // E
  const int*   dst       = (const int*)d_in[11];    // E
  const int*   neg_dst   = (const int*)d_in[12];    // E*K
  float* out = (float*)d_out;                       // E + E*K

  // ws layout: h (N*H f32) | s1 (N*H f32) | off (N+1 i32) | gsrc (E i32)
  // deg and cursor alias the s1 region (dead before aggregate writes s1).
  float* h   = (float*)d_ws;
  float* s1  = h + (size_t)NV * HD;
  int*   off = (int*)(s1 + (size_t)NV * HD);
  int*   gsrc = off + (NV + 1);
  int*   deg = (int*)s1;           // alias: s1[0 .. NV)
  int*   cursor = ((int*)s1) + NV; // alias: s1[NV .. 2NV)

  hipMemsetAsync(deg, 0, (size_t)NV * sizeof(int), stream);
  embed_kernel<<<1024, 256, 0, stream>>>(node_feat, emb_w, emb_b, h);
  hist_kernel<<<(EV + 255) / 256, 256, 0, stream>>>(dst, deg);
  scan_kernel<<<1, 1024, 0, stream>>>(deg, off);
  hipMemcpyAsync(cursor, off, (size_t)NV * sizeof(int),
                 hipMemcpyDeviceToDevice, stream);
  perm_kernel<<<(EV + 255) / 256, 256, 0, stream>>>(src, dst, cursor, gsrc);

  for (int i = 0; i < 2; i++) {
    aggregate_kernel<<<(NV + 3) / 4, 256, 0, stream>>>(h, gsrc, off, s1);
    combine_kernel<<<1024, 256, 0, stream>>>(
        h, s1, off, conv_w + (size_t)i * 2 * HD * HD, conv_b + i * HD,
        bn_gamma + i * HD, bn_beta + i * HD, bn_mean + i * HD, bn_var + i * HD);
  }

  score_kernel<<<((size_t)EV * 8 + 255) / 256, 256, 0, stream>>>(
      h, src, dst, neg_dst, w_rel, out);
}

// Round 9
// 559.883 us; speedup vs baseline: 3.8430x; 1.0170x over previous
//
#include <hip/hip_runtime.h>

#define NV 50000
#define EV 800000
#define INF 128
#define HD 64
#define KNEG 5
#define EMB_BLOCKS 1024

// ------- embed + hist fused: h = feat @ emb_w + emb_b; deg histogram --
__global__ __launch_bounds__(256) void embed_hist_kernel(
    const float* __restrict__ feat, const float* __restrict__ W,
    const float* __restrict__ b, float* __restrict__ h,
    const int* __restrict__ dst, int* __restrict__ deg) {
  __shared__ float sW[INF * HD];   // 32 KB
  __shared__ float sF[4][INF];     // 2 KB
  for (int i = threadIdx.x; i < INF * HD; i += 256) sW[i] = W[i];
  const int f = threadIdx.x & 63;
  const int sub = threadIdx.x >> 6;   // wave id within block (wave-uniform)
  const float bias = b[f];
  __syncthreads();
  const int ngroups = (NV + 3) / 4;
  for (int g = blockIdx.x; g < ngroups; g += gridDim.x) {
    const int n0 = g * 4;
    for (int i = threadIdx.x; i < 4 * INF; i += 256) {
      const int nn = n0 + (i >> 7);
      sF[i >> 7][i & 127] = (nn < NV) ? feat[nn * INF + (i & 127)] : 0.f;
    }
    __syncthreads();
    const int n = n0 + sub;
    if (n < NV) {
      float acc = bias;
#pragma unroll 8
      for (int k = 0; k < INF; k++) acc += sF[sub][k] * sW[k * HD + f];
      h[n * HD + f] = acc;
    }
    __syncthreads();
  }
  // hist tail: grid-stride over edges (overlaps with other blocks' embed)
  for (int e = blockIdx.x * 256 + threadIdx.x; e < EV; e += gridDim.x * 256)
    atomicAdd(&deg[dst[e]], 1);
}

// ------- exclusive scan deg -> off AND cursor, single pass ------------
// Thread t owns SCAN_C contiguous elements; one block-scan of thread sums.
#define SCAN_C ((NV + 1023) / 1024)   // 49
__global__ __launch_bounds__(1024) void scan_kernel(
    const int* __restrict__ deg, int* __restrict__ off,
    int* __restrict__ cursor) {
  __shared__ int wsum[16];
  __shared__ int stotal;
  const int tid = threadIdx.x;
  const int lane = tid & 63;
  const int w = tid >> 6;
  const int i0 = tid * SCAN_C;
  int loc[SCAN_C];
  int tsum = 0;
#pragma unroll
  for (int c = 0; c < SCAN_C; c++) {
    const int i = i0 + c;
    loc[c] = (i < NV) ? deg[i] : 0;
    tsum += loc[c];
  }
  int s = tsum;                       // wave-inclusive scan of thread sums
#pragma unroll
  for (int ofs = 1; ofs < 64; ofs <<= 1) {
    int x = __shfl_up(s, ofs, 64);
    if (lane >= ofs) s += x;
  }
  if (lane == 63) wsum[w] = s;
  __syncthreads();
  if (w == 0) {
    int t2 = (lane < 16) ? wsum[lane] : 0;
#pragma unroll
    for (int ofs = 1; ofs < 16; ofs <<= 1) {
      int x = __shfl_up(t2, ofs, 64);
      if (lane >= ofs) t2 += x;
    }
    if (lane < 16) wsum[lane] = t2;
    if (lane == 15) stotal = t2;
  }
  __syncthreads();
  int run = ((w > 0) ? wsum[w - 1] : 0) + s - tsum;  // thread-exclusive
#pragma unroll
  for (int c = 0; c < SCAN_C; c++) {
    const int i = i0 + c;
    if (i < NV) { off[i] = run; cursor[i] = run; }
    run += loc[c];
  }
  if (tid == 0) off[NV] = stotal;
}

// ------- CSR perm: gsrc[pos] = src[e], grouped by dst -----------------
__global__ __launch_bounds__(256) void perm_kernel(
    const int* __restrict__ src, const int* __restrict__ dst,
    int* __restrict__ cursor, int* __restrict__ gsrc) {
  const int e = blockIdx.x * 256 + threadIdx.x;
  if (e < EV) {
    const int pos = atomicAdd(&cursor[dst[e]], 1);
    gsrc[pos] = src[e];
  }
}

// ------- fused aggregate + combine: hin -> hout (ping-pong) -----------
// Phase 1 = r8's verified aggregate (all __shfl under full exec).
// Hand-off via wave-private LDS row (in-order DS pipe, no barrier).
// Phase 2 = r5's verified combine inner-loop structure.
__global__ __launch_bounds__(256) void aggcomb_kernel(
    const float* __restrict__ hin, float* __restrict__ hout,
    const int* __restrict__ gsrc, const int* __restrict__ off,
    const float* __restrict__ wconv, const float* __restrict__ cb,
    const float* __restrict__ gamma, const float* __restrict__ beta,
    const float* __restrict__ mean, const float* __restrict__ var) {
  __shared__ float sWs[HD * HD];    // 16 KB
  __shared__ float sWd[HD * HD];    // 16 KB
  __shared__ float sRow[4][2 * HD]; // per-wave: s1 row | h row (2 KB)
  for (int i = threadIdx.x; i < HD * HD / 4; i += 256) {
    ((float4*)sWs)[i] = ((const float4*)wconv)[i];
    ((float4*)sWd)[i] = ((const float4*)(wconv + HD * HD))[i];
  }
  const int wave = threadIdx.x >> 6;
  const int lane = threadIdx.x & 63;
  const int sub = lane >> 4;   // edge slot 0..3
  const int q = lane & 15;     // float4 slot within row
  const int f = lane;          // output feature in phase 2
  const float cbf = cb[f];
  const float gf = gamma[f];
  const float btf = beta[f];
  const float mf = mean[f];
  const float inv = rsqrtf(var[f] + 1e-3f);
  __syncthreads();             // weights staged (only barrier)
  const float4* hp = (const float4*)hin;
  for (int n = blockIdx.x * 4 + wave; n < NV; n += gridDim.x * 4) {
    const int j0 = off[n], j1 = off[n + 1];
    const int deg = j1 - j0;
    const float hv = hin[(size_t)n * HD + lane];  // own h row element
    float4 acc0 = make_float4(0.f, 0.f, 0.f, 0.f);
    float4 acc1 = make_float4(0.f, 0.f, 0.f, 0.f);
    for (int base = 0; base < deg; base += 64) {
      const int cnt = min(64, deg - base);        // wave-uniform
      const int my = (lane < cnt) ? gsrc[j0 + base + lane] : 0;
      int k = 0;
      for (; k + 8 <= cnt; k += 8) {              // uniform: full exec
        const int a0 = __shfl(my, k + sub, 64);
        const int a1 = __shfl(my, k + 4 + sub, 64);
        const float4 v0 = hp[(size_t)a0 * 16 + q];
        const float4 v1 = hp[(size_t)a1 * 16 + q];
        acc0.x += v0.x; acc0.y += v0.y; acc0.z += v0.z; acc0.w += v0.w;
        acc1.x += v1.x; acc1.y += v1.y; acc1.z += v1.z; acc1.w += v1.w;
      }
      for (; k + 4 <= cnt; k += 4) {              // uniform: full exec
        const int a0 = __shfl(my, k + sub, 64);
        const float4 v0 = hp[(size_t)a0 * 16 + q];
        acc0.x += v0.x; acc0.y += v0.y; acc0.z += v0.z; acc0.w += v0.w;
      }
      {
        // tail: shfl hoisted out of the divergent guard (clamped index)
        const int idx = k + sub;
        const int a0 = __shfl(my, (idx < cnt) ? idx : 0, 64);
        if (idx < cnt) {
          const float4 v0 = hp[(size_t)a0 * 16 + q];
          acc1.x += v0.x; acc1.y += v0.y; acc1.z += v0.z; acc1.w += v0.w;
        }
      }
    }
    acc0.x += acc1.x; acc0.y += acc1.y; acc0.z += acc1.z; acc0.w += acc1.w;
#pragma unroll
    for (int m = 16; m <= 32; m <<= 1) {
      acc0.x += __shfl_xor(acc0.x, m, 64);
      acc0.y += __shfl_xor(acc0.y, m, 64);
      acc0.z += __shfl_xor(acc0.z, m, 64);
      acc0.w += __shfl_xor(acc0.w, m, 64);
    }
    // hand-off: wave-private LDS row (in-order DS pipe; no barrier)
    if (sub == 0) ((float4*)&sRow[wave][0])[q] = acc0;  // s1 row
    sRow[wave][HD + lane] = hv;                          // h row
    float a1 = 0.f, a2 = 0.f;
#pragma unroll 8
    for (int k = 0; k < HD; k++) {
      a1 += sRow[wave][k] * sWs[k * HD + f];
      a2 += sRow[wave][HD + k] * sWd[k * HD + f];
    }
    const float d = (float)deg;
    const float agg = a1 + d * a2 + d * cbf;
    const float sig = 1.f / (1.f + __expf(-agg));
    const float sp = fmaxf(hv, 0.f) + log1pf(__expf(-fabsf(hv)));
    float x = sig + sp;
    x = gf * (x - mf) * inv + btf;
    hout[(size_t)n * HD + f] = fmaxf(x, 0.f);
  }
}

// ------- scores: 8 lanes per edge, 2 float4 per thread ----------------
__global__ __launch_bounds__(256) void score_kernel(
    const float* __restrict__ h, const int* __restrict__ src,
    const int* __restrict__ dst, const int* __restrict__ neg_dst,
    const float* __restrict__ wrel, float* __restrict__ out) {
  const int tid = blockIdx.x * 256 + threadIdx.x;
  const int e = tid >> 3;       // 8 edges per wave
  const int q = tid & 7;        // covers float4 slots 2q, 2q+1
  if (e >= EV) return;
  const float4 w0 = ((const float4*)wrel)[2 * q];
  const float4 w1 = ((const float4*)wrel)[2 * q + 1];
  const int s = src[e];
  const int d = dst[e];
  int nd[KNEG];
#pragma unroll
  for (int r = 0; r < KNEG; r++) nd[r] = neg_dst[e * KNEG + r];

  const float4* hp = (const float4*)h;
  const float4 sv0 = hp[(size_t)s * 16 + 2 * q];
  const float4 sv1 = hp[(size_t)s * 16 + 2 * q + 1];
  const float4 dv0 = hp[(size_t)d * 16 + 2 * q];
  const float4 dv1 = hp[(size_t)d * 16 + 2 * q + 1];
  float4 nv0[KNEG], nv1[KNEG];
#pragma unroll
  for (int r = 0; r < KNEG; r++) {
    nv0[r] = hp[(size_t)nd[r] * 16 + 2 * q];
    nv1[r] = hp[(size_t)nd[r] * 16 + 2 * q + 1];
  }
  const float s0x = sv0.x * w0.x, s0y = sv0.y * w0.y,
              s0z = sv0.z * w0.z, s0w = sv0.w * w0.w;
  const float s1x = sv1.x * w1.x, s1y = sv1.y * w1.y,
              s1z = sv1.z * w1.z, s1w = sv1.w * w1.w;

  float p = s0x * dv0.x + s0y * dv0.y + s0z * dv0.z + s0w * dv0.w
          + s1x * dv1.x + s1y * dv1.y + s1z * dv1.z + s1w * dv1.w;
#pragma unroll
  for (int m = 4; m; m >>= 1) p += __shfl_xor(p, m, 64);
  if (q == 0) out[e] = p;

#pragma unroll
  for (int r = 0; r < KNEG; r++) {
    float pn = s0x * nv0[r].x + s0y * nv0[r].y + s0z * nv0[r].z + s0w * nv0[r].w
             + s1x * nv1[r].x + s1y * nv1[r].y + s1z * nv1[r].z + s1w * nv1[r].w;
#pragma unroll
    for (int m = 4; m; m >>= 1) pn += __shfl_xor(pn, m, 64);
    if (q == 0) out[(size_t)EV + (size_t)e * KNEG + r] = pn;
  }
}

extern "C" void kernel_launch(void* const* d_in, const int* in_sizes, int n_in,
                              void* d_out, int out_size, void* d_ws, size_t ws_size,
                              hipStream_t stream) {
  const float* node_feat = (const float*)d_in[0];   // N x 128
  const float* emb_w     = (const float*)d_in[1];   // 128 x 64
  const float* emb_b     = (const float*)d_in[2];   // 64
  const float* conv_w    = (const float*)d_in[3];   // L x 128 x 64
  const float* conv_b    = (const float*)d_in[4];   // L x 64
  const float* bn_gamma  = (const float*)d_in[5];   // L x 64
  const float* bn_beta   = (const float*)d_in[6];
  const float* bn_mean   = (const float*)d_in[7];
  const float* bn_var    = (const float*)d_in[8];
  const float* w_rel     = (const float*)d_in[9];   // 64
  const int*   src       = (const int*)d_in[10];    // E
  const int*   dst       = (const int*)d_in[11];    // E
  const int*   neg_dst   = (const int*)d_in[12];    // E*K
  float* out = (float*)d_out;                       // E + E*K

  // ws layout: h (N*H f32) | h2 (N*H f32) | off (N+1 i32) | gsrc (E i32)
  // deg and cursor alias the h2 region (dead before aggcomb writes h2).
  float* h   = (float*)d_ws;
  float* h2  = h + (size_t)NV * HD;
  int*   off = (int*)(h2 + (size_t)NV * HD);
  int*   gsrc = off + (NV + 1);
  int*   deg = (int*)h2;           // alias: h2[0 .. NV)
  int*   cursor = ((int*)h2) + NV; // alias: h2[NV .. 2NV)

  hipMemsetAsync(deg, 0, (size_t)NV * sizeof(int), stream);
  embed_hist_kernel<<<EMB_BLOCKS, 256, 0, stream>>>(node_feat, emb_w, emb_b, h,
                                                    dst, deg);
  scan_kernel<<<1, 1024, 0, stream>>>(deg, off, cursor);
  perm_kernel<<<(EV + 255) / 256, 256, 0, stream>>>(src, dst, cursor, gsrc);

  // layer 0: h -> h2 ; layer 1: h2 -> h  (ping-pong; h2 reuses dead scratch)
  aggcomb_kernel<<<1024, 256, 0, stream>>>(
      h, h2, gsrc, off, conv_w, conv_b,
      bn_gamma, bn_beta, bn_mean, bn_var);
  aggcomb_kernel<<<1024, 256, 0, stream>>>(
      h2, h, gsrc, off, conv_w + 2 * HD * HD, conv_b + HD,
      bn_gamma + HD, bn_beta + HD, bn_mean + HD, bn_var + HD);

  score_kernel<<<((size_t)EV * 8 + 255) / 256, 256, 0, stream>>>(
      h, src, dst, neg_dst, w_rel, out);
}